// Round 1
// baseline (193.887 us; speedup 1.0000x reference)
//
#include <hip/hip_runtime.h>

// Painting composite: canvas = scan over 256 strokes of
//   canvas = canvas*(1-a) + a*stroke,  a = stroke[3]
// canvas init = background with alpha channel forced to 1.0.
// Memory-bound streaming kernel: 1 GiB stroke read dominates.

#define HW_PIX (512 * 512)
#define N_STROKES 256

__global__ __launch_bounds__(256) void painting_composite_kernel(
    const float* __restrict__ strokes,   // [256, 4, H, W]
    const float* __restrict__ bg,        // [1, 4, H, W]
    float* __restrict__ out)             // [1, 4, H, W]
{
    const int p = blockIdx.x * blockDim.x + threadIdx.x;  // pixel index in [0, HW)

    // Canvas registers: channels 0..2 from background, alpha forced to 1.0
    float c0 = bg[0 * HW_PIX + p];
    float c1 = bg[1 * HW_PIX + p];
    float c2 = bg[2 * HW_PIX + p];
    float c3 = 1.0f;

    const float* sp = strokes + p;
#pragma unroll 4
    for (int s = 0; s < N_STROKES; ++s) {
        // Coalesced plane reads: lane i -> sp + i (contiguous within each plane)
        const float s0 = sp[0 * HW_PIX];
        const float s1 = sp[1 * HW_PIX];
        const float s2 = sp[2 * HW_PIX];
        const float a  = sp[3 * HW_PIX];  // alpha plane (OPACITY_FACTOR = 1.0)

        // canvas*(1-a) + a*s  ==  canvas + a*(s - canvas)
        c0 += a * (s0 - c0);
        c1 += a * (s1 - c1);
        c2 += a * (s2 - c2);
        c3 += a * (a  - c3);  // stroke's own alpha composites into canvas alpha

        sp += 4 * HW_PIX;
    }

    out[0 * HW_PIX + p] = c0;
    out[1 * HW_PIX + p] = c1;
    out[2 * HW_PIX + p] = c2;
    out[3 * HW_PIX + p] = c3;
}

extern "C" void kernel_launch(void* const* d_in, const int* in_sizes, int n_in,
                              void* d_out, int out_size, void* d_ws, size_t ws_size,
                              hipStream_t stream) {
    const float* strokes = (const float*)d_in[0];  // 256*4*512*512 f32
    const float* bg      = (const float*)d_in[1];  // 1*4*512*512 f32
    float* out           = (float*)d_out;          // 1*4*512*512 f32

    const int threads = 256;
    const int blocks  = HW_PIX / threads;  // 262144 / 256 = 1024
    painting_composite_kernel<<<blocks, threads, 0, stream>>>(strokes, bg, out);
}

// Round 2
// 153.932 us; speedup vs baseline: 1.2596x; 1.2596x over previous
//
#include <hip/hip_runtime.h>

// Painting composite: canvas = scan over 256 strokes of
//   canvas = canvas*(1-a) + a*stroke,  a = stroke[3] (OPACITY_FACTOR = 1.0)
// canvas init = background with alpha forced to 1.0.
//
// Memory-bound: 1 GiB stroke stream dominates. Roofline @ ~6.3-6.6 TB/s
// achievable -> ~165-172 us. R0 (scalar dword loads) = 194 us / 5.58 TB/s.
// This round: float4 (dwordx4) plane loads, 4 pixels/thread, nontemporal
// on the zero-reuse stroke stream.

#define HW_PIX (512 * 512)
#define HWQ (HW_PIX / 4)   // float4 groups per plane
#define N_STROKES 256

typedef float f4 __attribute__((ext_vector_type(4)));

__global__ __launch_bounds__(256) void painting_composite_kernel(
    const f4* __restrict__ strokes,   // [256, 4, HWQ] as float4
    const f4* __restrict__ bg,        // [1, 4, HWQ]
    f4* __restrict__ out)             // [1, 4, HWQ]
{
    const int q = blockIdx.x * blockDim.x + threadIdx.x;  // float4-group in [0, HWQ)

    // Canvas registers: RGB from background, alpha forced to 1.0
    f4 c0 = bg[0 * HWQ + q];
    f4 c1 = bg[1 * HWQ + q];
    f4 c2 = bg[2 * HWQ + q];
    f4 c3 = (f4){1.0f, 1.0f, 1.0f, 1.0f};

    const f4* sp = strokes + q;
#pragma unroll 4
    for (int s = 0; s < N_STROKES; ++s) {
        // Coalesced dwordx4 plane reads; nontemporal (stream, zero reuse)
        const f4 s0 = __builtin_nontemporal_load(sp + 0 * HWQ);
        const f4 s1 = __builtin_nontemporal_load(sp + 1 * HWQ);
        const f4 s2 = __builtin_nontemporal_load(sp + 2 * HWQ);
        const f4 a  = __builtin_nontemporal_load(sp + 3 * HWQ);

        // canvas*(1-a) + a*s  ==  canvas + a*(s - canvas)
        c0 += a * (s0 - c0);
        c1 += a * (s1 - c1);
        c2 += a * (s2 - c2);
        c3 += a * (a  - c3);  // stroke alpha composites into canvas alpha

        sp += 4 * HWQ;
    }

    out[0 * HWQ + q] = c0;
    out[1 * HWQ + q] = c1;
    out[2 * HWQ + q] = c2;
    out[3 * HWQ + q] = c3;
}

extern "C" void kernel_launch(void* const* d_in, const int* in_sizes, int n_in,
                              void* d_out, int out_size, void* d_ws, size_t ws_size,
                              hipStream_t stream) {
    const f4* strokes = (const f4*)d_in[0];  // 256*4*512*512 f32
    const f4* bg      = (const f4*)d_in[1];  // 1*4*512*512 f32
    f4* out           = (f4*)d_out;          // 1*4*512*512 f32

    const int threads = 256;
    const int blocks  = HWQ / threads;  // 65536 / 256 = 256 blocks
    painting_composite_kernel<<<blocks, threads, 0, stream>>>(strokes, bg, out);
}